// Round 12
// baseline (233.151 us; speedup 1.0000x reference)
//
#include <hip/hip_runtime.h>

#define D   256
#define BM  64      // rows per block; 4 waves EACH cover all 64 rows x 1/4 codes
#define BN  128     // codes per group

typedef __attribute__((ext_vector_type(8))) short v8s;   // 8 bf16 = 4 VGPR
typedef __attribute__((ext_vector_type(4))) float v4f;
#define MFMA16 __builtin_amdgcn_mfma_f32_16x16x32_bf16
// pin: B-loads issued above this point may not be crossed by the MFMAs below
#define SB0() __builtin_amdgcn_sched_barrier(0)

static __device__ inline unsigned short f2bf(float f) {          // RNE
    unsigned u = __float_as_uint(f);
    return (unsigned short)((u + 0x7fffu + ((u >> 16) & 1u)) >> 16);
}
static __device__ inline float bf2f(unsigned short s) {
    return __uint_as_float(((unsigned)s) << 16);
}

// ---------------- kernel 1a: exact c2 (+ zero the loss accumulator) ----------------
__global__ void vq_prep_c2(const float* __restrict__ cb, float* __restrict__ c2,
                           float* __restrict__ loss) {
    const int row  = blockIdx.x;
    const int lane = threadIdx.x;  // 64
    if (row == 0 && lane == 0) loss[0] = 0.0f;
    const float4 v = *reinterpret_cast<const float4*>(cb + (size_t)row * D + lane * 4);
    float s = v.x * v.x + v.y * v.y + v.z * v.z + v.w * v.w;
    #pragma unroll
    for (int off = 32; off > 0; off >>= 1) s += __shfl_down(s, off, 64);
    if (lane == 0) c2[row] = s;
}

// ---------------- kernel 1b: codebook -> bf16 hi/lo, QUARTER-fragment-major ----------------
// Storage position p (0..65535), 16 B granule:
//   lane=p&63, f=(p>>6)&3, ng=(p>>8)&3, s=p>>10 (stage/chunk 0..63)
//   nt=f&1, ksk=f>>1, g=s>>2, cc=s&3
//   code n = g*128 + ng*32 + nt*16 + (lane&15)
//   k0     = cc*64 + ksk*32 + (lane>>4)*8      (8 bf16)
// A wave's B-fragment (s, ng, dtype, f) is 64 consecutive granules: lane l at
// byte l*16 — perfectly coalesced 1 KB global_load_dwordx4, and the granule
// layout is exactly the mfma_16x16x32 B-operand mapping (col=lane&15,
// k=(lane>>4)*8+j), so loads land MFMA-ready.
__global__ void vq_prep_frag(const float* __restrict__ cb,
                             unsigned short* __restrict__ cbh,
                             unsigned short* __restrict__ cbl) {
    const int p    = blockIdx.x * 256 + threadIdx.x;   // grid 256 -> 65536
    const int lane = p & 63;
    const int f    = (p >> 6) & 3;
    const int ng   = (p >> 8) & 3;
    const int s    = p >> 10;
    const int nt = f & 1, ksk = f >> 1;
    const int g = s >> 2, cc = s & 3;
    const int n  = g * 128 + ng * 32 + nt * 16 + (lane & 15);
    const int k0 = cc * 64 + ksk * 32 + (lane >> 4) * 8;
    const float* src = cb + (size_t)n * D + k0;
    const float4 f0 = *reinterpret_cast<const float4*>(src);
    const float4 f1 = *reinterpret_cast<const float4*>(src + 4);
    const float fv[8] = {f0.x, f0.y, f0.z, f0.w, f1.x, f1.y, f1.z, f1.w};
    v8s h, l;
    #pragma unroll
    for (int j = 0; j < 8; ++j) {
        unsigned short hb = f2bf(fv[j]);
        h[j] = (short)hb;
        l[j] = (short)f2bf(fv[j] - bf2f(hb));
    }
    *reinterpret_cast<v8s*>(cbh + (size_t)p * 8) = h;
    *reinterpret_cast<v8s*>(cbl + (size_t)p * 8) = l;
}

// ---------------- kernel 2: barrier-free MFMA argmin, 64 rows/wave ----------------
// Each of the 4 waves covers ALL 64 block rows x a fixed QUARTER of every code
// group (ng=w). Rows-per-rowset doubles 32->64, halving total L2 B-traffic to
// 1 GB (the r10/r11 limiter: 2 GB demand > per-CU L2 share at the MFMA floor).
// Per chunk/wave: 8 coalesced 1 KB loads (next chunk, ping-pong banks) then
// 48 MFMAs (~930 cyc/SIMD) — depth-1 prefetch slack >> L2 latency. ~404 VGPR
// -> 1 wave/SIMD, which saturates the matrix pipe (1 MFMA / ~19 cyc / SIMD).
// No barriers, no shared mutable state until the epilogue: replay-safe.
__global__ __launch_bounds__(256, 1) void vq_argmin_mfma(
        const float* __restrict__ x, const float* __restrict__ cb,
        const unsigned short* __restrict__ cbh, const unsigned short* __restrict__ cbl,
        const float* __restrict__ c2, float* __restrict__ idx_out,
        float* __restrict__ qout, float* __restrict__ loss, float scale, int N) {
    __shared__ float red_v[64 * 64];   // 16 KB
    __shared__ int   red_i[64 * 64];   // 16 KB
    __shared__ float c2s[2048];        // 8 KB
    __shared__ int   idx_sh[64];
    __shared__ float wsum[4];

    const int tid  = threadIdx.x;
    const int w    = tid >> 6;      // 4 waves
    const int lane = tid & 63;
    const int col  = lane & 15;     // MFMA col / A-row selector
    const int quad = lane >> 4;     // k-octet selector
    const int ng   = w;             // 0..3 : 32-code quarter of each group
    const int m0   = blockIdx.x * BM;
    const int n_groups = N >> 7;

    // per-lane fragment base: stage block 16384 B; ng quarter 4096 B; frag f
    // at +f*1024; lane at +lane*16.
    const char* bh = (const char*)cbh + (size_t)ng * 4096 + (size_t)lane * 16;
    const char* bl = (const char*)cbl + (size_t)ng * 4096 + (size_t)lane * 16;

#define LOADB(CH, CL, S)                                                       \
    {                                                                          \
        const char* ph = bh + (size_t)(S) * 16384;                             \
        const char* pl = bl + (size_t)(S) * 16384;                             \
        _Pragma("unroll")                                                      \
        for (int f = 0; f < 4; ++f) {                                          \
            CH[f] = *reinterpret_cast<const v8s*>(ph + f * 1024);              \
            CL[f] = *reinterpret_cast<const v8s*>(pl + f * 1024);              \
        }                                                                      \
    }

    // B register banks (ping-pong by chunk parity): 16 v8s = 64 VGPR
    v8s chA[4], clA[4], chB[4], clB[4];
    LOADB(chA, clA, 0);                 // stage-0 loads fly during setup below

    // ---- c2 -> LDS ----
    {
        const int o = tid * 8;
        if (o < N) {
            const float4 a = *reinterpret_cast<const float4*>(c2 + o);
            const float4 b = *reinterpret_cast<const float4*>(c2 + o + 4);
            *reinterpret_cast<float4*>(&c2s[o])     = a;
            *reinterpret_cast<float4*>(&c2s[o + 4]) = b;
        }
    }

    // ---- A-frags: ALL 64 rows (mt 0..3), full K, hi+lo (256 VGPR) ----
    v8s xh[4][8], xl[4][8];
    #pragma unroll
    for (int mt = 0; mt < 4; ++mt) {
        const float* xr = x + (size_t)(m0 + mt * 16 + col) * D;
        #pragma unroll
        for (int ks = 0; ks < 8; ++ks) {
            const int kb = ks * 32 + quad * 8;
            const float4 f0 = *reinterpret_cast<const float4*>(xr + kb);
            const float4 f1 = *reinterpret_cast<const float4*>(xr + kb + 4);
            float fv[8] = {f0.x, f0.y, f0.z, f0.w, f1.x, f1.y, f1.z, f1.w};
            v8s h, l;
            #pragma unroll
            for (int j = 0; j < 8; ++j) {
                unsigned short hb = f2bf(fv[j]);
                h[j] = (short)hb;
                l[j] = (short)f2bf(fv[j] - bf2f(hb));
            }
            xh[mt][ks] = h; xl[mt][ks] = l;
        }
    }

    float runmin[4][4];
    int   runidx[4][4];
    #pragma unroll
    for (int mt = 0; mt < 4; ++mt)
        #pragma unroll
        for (int r = 0; r < 4; ++r) { runmin[mt][r] = 3.4e38f; runidx[mt][r] = 0; }

    v4f acc[2][4];   // [nt][mt]
    #pragma unroll
    for (int nt = 0; nt < 2; ++nt)
        #pragma unroll
        for (int mt = 0; mt < 4; ++mt) acc[nt][mt] = 0.0f;

    __syncthreads();   // publish c2s (one-time)

#define COMP(CH, CL, CC)                                                       \
    _Pragma("unroll")                                                          \
    for (int ksk = 0; ksk < 2; ++ksk) {                                        \
        const int ks = (CC) * 2 + ksk;                                         \
        _Pragma("unroll")                                                      \
        for (int nt = 0; nt < 2; ++nt) {                                       \
            const v8s ch = CH[ksk * 2 + nt];                                   \
            const v8s cl = CL[ksk * 2 + nt];                                   \
            _Pragma("unroll")                                                  \
            for (int mt = 0; mt < 4; ++mt) {                                   \
                acc[nt][mt] = MFMA16(xh[mt][ks], ch, acc[nt][mt], 0, 0, 0);    \
                acc[nt][mt] = MFMA16(xl[mt][ks], ch, acc[nt][mt], 0, 0, 0);    \
                acc[nt][mt] = MFMA16(xh[mt][ks], cl, acc[nt][mt], 0, 0, 0);    \
            }                                                                  \
        }                                                                      \
    }

    for (int g = 0; g < n_groups; ++g) {
        const int s0 = g * 4;
        LOADB(chB, clB, s0 + 1); SB0();
        COMP(chA, clA, 0);
        LOADB(chA, clA, s0 + 2); SB0();
        COMP(chB, clB, 1);
        LOADB(chB, clB, s0 + 3); SB0();
        COMP(chA, clA, 2);
        // (g==15 prefetches stage 64 -> 16 KB pad after cbl; never consumed)
        LOADB(chA, clA, s0 + 4); SB0();
        COMP(chB, clB, 3);

        // finalize this n-group (registers + read-only c2s)
        #pragma unroll
        for (int nt = 0; nt < 2; ++nt) {
            const int n = g * BN + ng * 32 + nt * 16 + col;
            const float c2n = c2s[n];
            #pragma unroll
            for (int mt = 0; mt < 4; ++mt) {
                #pragma unroll
                for (int r = 0; r < 4; ++r) {
                    const float s = c2n - 2.0f * acc[nt][mt][r];
                    if (s < runmin[mt][r]) { runmin[mt][r] = s; runidx[mt][r] = n; }
                }
                acc[nt][mt] = 0.0f;
            }
        }
    }
#undef LOADB
#undef COMP

    // ---- merge: row = mt*16 + quad*4 + r (0..63); 64 candidates/row ----
    // slot = ng*16 + (col ^ (row & 15)) : bijective per (row, ng), bank-spread.
    __syncthreads();
    #pragma unroll
    for (int mt = 0; mt < 4; ++mt)
        #pragma unroll
        for (int r = 0; r < 4; ++r) {
            const int row  = mt * 16 + quad * 4 + r;
            const int slot = ng * 16 + (col ^ (row & 15));
            red_v[row * 64 + slot] = runmin[mt][r];
            red_i[row * 64 + slot] = runidx[mt][r];
        }
    __syncthreads();
    float best = 3.4e38f;
    int   bidx = 0;
    if (tid < 64) {
        #pragma unroll 4
        for (int t = 0; t < 64; ++t) {
            const int  sl = (t & 48) + ((t ^ tid) & 15);
            const float v = red_v[tid * 64 + sl];
            const int  id = red_i[tid * 64 + sl];
            if (v < best || (v == best && id < bidx)) { best = v; bidx = id; }
        }
        idx_out[m0 + tid] = (float)bidx;
        idx_sh[tid] = bidx;
    }
    __syncthreads();

    // ---- fused gather + loss over this block's 64 rows (x tile is L2-hot) ----
    const float* xg2 = x + (size_t)m0 * D;
    float s = 0.0f;
    #pragma unroll
    for (int i = 0; i < 16; ++i) {
        const int gix = i * 256 + tid;      // float4-granule, 4096 total
        const int row = gix >> 6;
        const int k4  = (gix & 63) * 4;
        const int idx = idx_sh[row];
        const float4 c  = *reinterpret_cast<const float4*>(cb  + (size_t)idx * D + k4);
        const float4 xv = *reinterpret_cast<const float4*>(xg2 + (size_t)row * D + k4);
        *reinterpret_cast<float4*>(qout + (size_t)(m0 + row) * D + k4) = c;
        const float dx = c.x - xv.x, dy = c.y - xv.y, dz = c.z - xv.z, dw = c.w - xv.w;
        s += dx * dx + dy * dy + dz * dz + dw * dw;
    }
    #pragma unroll
    for (int off = 32; off > 0; off >>= 1) s += __shfl_down(s, off, 64);
    if ((tid & 63) == 0) wsum[tid >> 6] = s;
    __syncthreads();
    if (tid == 0) {
        atomicAdd(loss, (wsum[0] + wsum[1] + wsum[2] + wsum[3]) * scale);
    }
}

extern "C" void kernel_launch(void* const* d_in, const int* in_sizes, int n_in,
                              void* d_out, int out_size, void* d_ws, size_t ws_size,
                              hipStream_t stream) {
    const float* x  = (const float*)d_in[0];
    const float* cb = (const float*)d_in[1];
    const int M = in_sizes[0] / D;   // 32768
    const int N = in_sizes[1] / D;   // 2048

    float* qout    = (float*)d_out;
    float* idx_out = qout + (size_t)M * D;
    float* loss    = idx_out + M;

    // ws layout (bytes): c2 [0,8K) | cbh [8K,+1M) | cbl [+1M) | pad 16K
    // (pad absorbs the branchless last-iteration overshoot prefetch)
    char* wsb = (char*)d_ws;
    float*          c2  = (float*)wsb;
    unsigned short* cbh = (unsigned short*)(wsb + 8192);
    unsigned short* cbl = cbh + (size_t)N * D;

    vq_prep_c2<<<N, 64, 0, stream>>>(cb, c2, loss);
    vq_prep_frag<<<(N * D * 2 / 16) / 256, 256, 0, stream>>>(cb, cbh, cbl);
    const float scale = 2.0f / (float)((size_t)M * D);
    vq_argmin_mfma<<<M / BM, 256, 0, stream>>>(x, cb, cbh, cbl, c2, idx_out, qout,
                                               loss, scale, N);
}